// Round 20
// baseline (273.225 us; speedup 1.0000x reference)
//
#include <hip/hip_runtime.h>

#define D        128
#define KCODES   2048
#define NROWS    32768
#define BATCH    8192

typedef _Float16 f16x8 __attribute__((ext_vector_type(8)));
typedef float    f32x4 __attribute__((ext_vector_type(4)));

#define MFMA16(a, b, c) __builtin_amdgcn_mfma_f32_16x16x32_f16((a), (b), (c), 0, 0, 0)
#define INV2048 4.8828125e-4f

// min-reduce a packed float across each 16-lane row via DPP row_ror (pure VALU)
static __device__ __forceinline__ float dppmin16(float s) {
    int t;
    t = __builtin_amdgcn_update_dpp(0, __float_as_int(s), 0x121, 0xf, 0xf, true);
    s = fminf(s, __int_as_float(t));
    t = __builtin_amdgcn_update_dpp(0, __float_as_int(s), 0x122, 0xf, 0xf, true);
    s = fminf(s, __int_as_float(t));
    t = __builtin_amdgcn_update_dpp(0, __float_as_int(s), 0x124, 0xf, 0xf, true);
    s = fminf(s, __int_as_float(t));
    t = __builtin_amdgcn_update_dpp(0, __float_as_int(s), 0x128, 0xf, 0xf, true);
    s = fminf(s, __int_as_float(t));
    return s;
}

// ---------------------------------------------------------------------------
// Kernel A: W -> (wh, wl) fp16 hi/lo in 16x16x32 fragment-linear layout +
// fp32 ||W||^2.  (layout verified by absmax<=1 in R11-R19)
// ---------------------------------------------------------------------------
__global__ void wconv_kernel(const float* __restrict__ W,
                             _Float16* __restrict__ whf, _Float16* __restrict__ wlf,
                             float* __restrict__ wnorm) {
    int gid = blockIdx.x * 256 + threadIdx.x;    // 32768 = 2048 codes x 16 slots
    int n = gid >> 4, s = gid & 15;
    const float4* src = (const float4*)(W + (size_t)n * D + s * 8);
    float4 a = src[0], b = src[1];
    float va[8] = {a.x, a.y, a.z, a.w, b.x, b.y, b.z, b.w};
    f16x8 hi, lo;
    float ss = 0.0f;
#pragma unroll
    for (int j = 0; j < 8; ++j) {
        _Float16 h = (_Float16)va[j];
        hi[j] = h;
        lo[j] = (_Float16)((va[j] - (float)h) * 2048.0f);
        ss += va[j] * va[j];
    }
    size_t idx = ((size_t)((n >> 4) * 4 + (s >> 2)) * 64 + (s & 3) * 16 + (n & 15));
    ((f16x8*)whf)[idx] = hi;
    ((f16x8*)wlf)[idx] = lo;
#pragma unroll
    for (int m = 1; m <= 8; m <<= 1) ss += __shfl_xor(ss, m);
    if (s == 0) wnorm[n] = ss;
}

// ---------------------------------------------------------------------------
// Kernel A2: f -> (-2f) hi/lo fp16 in the same fragment-linear layout,
// plus fp32 ||f_n||^2 (for the loss; lets gather skip re-reading f).
// ---------------------------------------------------------------------------
__global__ void fconv_kernel(const float* __restrict__ f,
                             _Float16* __restrict__ fhf, _Float16* __restrict__ flf,
                             float* __restrict__ fnorm) {
    int gid = blockIdx.x * 256 + threadIdx.x;    // 524288 = 32768 rows x 16 slots
    int n = gid >> 4, s = gid & 15;
    const float4* src = (const float4*)(f + (size_t)n * D + s * 8);
    float4 a = src[0], b = src[1];
    float va[8] = {a.x, a.y, a.z, a.w, b.x, b.y, b.z, b.w};
    f16x8 hi, lo;
    float ss = 0.0f;
#pragma unroll
    for (int j = 0; j < 8; ++j) {
        ss += va[j] * va[j];
        float x = -2.0f * va[j];
        _Float16 h = (_Float16)x;
        hi[j] = h;
        lo[j] = (_Float16)((x - (float)h) * 2048.0f);
    }
    size_t idx = ((size_t)((n >> 4) * 4 + (s >> 2)) * 64 + (s & 3) * 16 + (n & 15));
    ((f16x8*)fhf)[idx] = hi;
    ((f16x8*)flf)[idx] = lo;
#pragma unroll
    for (int m = 1; m <= 8; m <<= 1) ss += __shfl_xor(ss, m);
    if (s == 0) fnorm[n] = ss;
}

// ---------------------------------------------------------------------------
// Kernel B: W-STATIONARY, f direct from global, barrier-free — 4 waves/SIMD.
// Grid 512 = 128 row-groups(256 rows) x 4 code-blocks(512 codes); cb = b&3
// (XCD-pinned: (b+8)&3 = b&3 under round-robin dispatch).
// Block 512 thr = 8 waves; 2 blocks/CU (VGPR 112x4=448<=512, LDS 8KBx2).
// Wave w owns 64 codes (wh+wl in 128 VGPRs); f frags via coalesced
// global_load_dwordx4 (L1/L2-served). NO staging, NO main-loop barriers.
// Per 16-row tile: 8 loads -> 48 MFMA (16 chains) -> fold + DPP reduce.
// ---------------------------------------------------------------------------
extern "C" __global__ void __launch_bounds__(512)
__attribute__((amdgpu_flat_work_group_size(512, 512)))
__attribute__((amdgpu_waves_per_eu(4, 4)))
vq_argmin(const _Float16* __restrict__ fhf, const _Float16* __restrict__ flf,
          const _Float16* __restrict__ whf, const _Float16* __restrict__ wlf,
          const float* __restrict__ wnorm,
          float* __restrict__ bsp, int* __restrict__ bcp) {
    __shared__ float mrg[8 * 256];           // 8 KB: [wave][block-local row]

    const int b   = blockIdx.x;
    const int cb  = b & 3;                   // code block 0..3 (XCD-pinned)
    const int rg  = b >> 2;                  // row group 0..127 (256 rows)
    const int tid = threadIdx.x;
    const int w   = tid >> 6, l = tid & 63;
    const int l15 = l & 15, lq = l >> 4;

    // ---- W fragments: 64 codes (4 ct-tiles), hi+lo, in registers (128 VGPR) ----
    f16x8 wh[4][4], wl[4][4];
    {
        const f16x8* whv = (const f16x8*)whf;
        const f16x8* wlv = (const f16x8*)wlf;
        const int n0 = cb * 32 + w * 4;
#pragma unroll
        for (int ct = 0; ct < 4; ++ct)
#pragma unroll
            for (int ks = 0; ks < 4; ++ks) {
                size_t idx = (size_t)((n0 + ct) * 4 + ks) * 64 + l;
                wh[ct][ks] = whv[idx];
                wl[ct][ks] = wlv[idx];
            }
    }
    float wv[4];
    unsigned mv[4];
#pragma unroll
    for (int ct = 0; ct < 4; ++ct) {
        wv[ct] = wnorm[cb * 512 + w * 64 + ct * 16 + l15];
        mv[ct] = (unsigned)(ct << 4) | (unsigned)l15;
    }

    // f fragment base for this row group (256 rows = 16 sixteen-row tiles)
    const f16x8* fhv = (const f16x8*)fhf + (size_t)rg * 4096;
    const f16x8* flv = (const f16x8*)flf + (size_t)rg * 4096;

    // ---- main loop: 16 tiles, no barriers; compiler prefetches across tiles ----
#pragma unroll 2
    for (int m = 0; m < 16; ++m) {
        f16x8 fhk[4], flk[4];
#pragma unroll
        for (int ks = 0; ks < 4; ++ks) {
            fhk[ks] = fhv[(m * 4 + ks) * 64 + l];
            flk[ks] = flv[(m * 4 + ks) * 64 + l];
        }

        f32x4 accC[4], accH[4];
#pragma unroll
        for (int ct = 0; ct < 4; ++ct)
#pragma unroll
            for (int r = 0; r < 4; ++r) { accC[ct][r] = 0.0f; accH[ct][r] = wv[ct]; }

#pragma unroll
        for (int ks = 0; ks < 4; ++ks) {
            __builtin_amdgcn_s_setprio(1);
            // 12 MFMAs, 16 chains live, same-chain gap 8
#pragma unroll
            for (int ct = 0; ct < 4; ++ct)
                accC[ct] = MFMA16(fhk[ks], wl[ct][ks], accC[ct]);
#pragma unroll
            for (int ct = 0; ct < 4; ++ct)
                accH[ct] = MFMA16(fhk[ks], wh[ct][ks], accH[ct]);
#pragma unroll
            for (int ct = 0; ct < 4; ++ct)
                accC[ct] = MFMA16(flk[ks], wh[ct][ks], accC[ct]);
            __builtin_amdgcn_s_setprio(0);
        }

        // ---- fold: per row-slot r, min over 4 ct, (ct,col) in low 6 bits ----
        float bestR[4] = {3.4e38f, 3.4e38f, 3.4e38f, 3.4e38f};
#pragma unroll
        for (int ct = 0; ct < 4; ++ct)
#pragma unroll
            for (int r = 0; r < 4; ++r) {
                float s = fmaf(accC[ct][r], INV2048, accH[ct][r]);
                unsigned pk = (__float_as_uint(s) & 0xFFFFFFC0u) | mv[ct];
                bestR[r] = fminf(bestR[r], __uint_as_float(pk));
            }
        // min over the 16 code-columns (DPP, VALU-only)
#pragma unroll
        for (int r = 0; r < 4; ++r) bestR[r] = dppmin16(bestR[r]);

        if (l15 == 0) {
            f32x4 v;
            v[0] = bestR[0]; v[1] = bestR[1]; v[2] = bestR[2]; v[3] = bestR[3];
            *(f32x4*)(mrg + w * 256 + m * 16 + lq * 4) = v;
        }
    }

    // ---- epilogue: merge 8 waves per row; decode packed meta -> code ----
    __syncthreads();
    if (tid < 256) {
        int row = tid;                        // 256 rows
        float s = mrg[row];
        int wBest = 0;
#pragma unroll
        for (int ww = 1; ww < 8; ++ww) {
            float s2 = mrg[ww * 256 + row];
            if (s2 < s) { s = s2; wBest = ww; }
        }
        unsigned bits = __float_as_uint(s);
        int code = cb * 512 + wBest * 64 + (int)((bits >> 4) & 3u) * 16 + (int)(bits & 15u);
        bsp[(size_t)cb * NROWS + rg * 256 + row] = s;
        bcp[(size_t)cb * NROWS + rg * 256 + row] = code;
    }
}

// ---------------------------------------------------------------------------
// Kernel C: merge the 4 code-block partials, gather W[j], write out; loss
// computed from the winning score + precomputed ||f||^2 (no f re-read).
// ---------------------------------------------------------------------------
__global__ void gather_kernel(const float* __restrict__ W,
                              const float* __restrict__ fnorm,
                              const float* __restrict__ bsp, const int* __restrict__ bcp,
                              float* __restrict__ loss, float* __restrict__ outv) {
    int b  = blockIdx.x;
    int wv = threadIdx.x >> 6;
    int l  = threadIdx.x & 63;
    int n  = b * 4 + wv;
    float s; int c;
    if (l < 4) { s = bsp[(size_t)l * NROWS + n]; c = bcp[(size_t)l * NROWS + n]; }
    else       { s = 3.4e38f; c = 0x7FFFFFFF; }
#pragma unroll
    for (int msk = 1; msk <= 2; msk <<= 1) {
        float s2 = __shfl_xor(s, msk);
        int   c2 = __shfl_xor(c, msk);
        if (s2 < s || (s2 == s && c2 < c)) { s = s2; c = c2; }
    }
    int j = __shfl(c, 0);
    float smin = __shfl(s, 0);
    float2 wj = reinterpret_cast<const float2*>(W + (size_t)j * D)[l];
    reinterpret_cast<float2*>(outv + (size_t)n * D)[l] = wj;
    __shared__ float lsm[4];
    if (l == 0) lsm[wv] = smin + fnorm[n];   // = ||f_n - W_j||^2 (+ ~1e-3)
    __syncthreads();
    if (threadIdx.x == 0)
        loss[b] = 0.3125f * (lsm[0] + lsm[1] + lsm[2] + lsm[3]);
}

// ---------------------------------------------------------------------------
extern "C" void kernel_launch(void* const* d_in, const int* in_sizes, int n_in,
                              void* d_out, int out_size, void* d_ws, size_t ws_size,
                              hipStream_t stream) {
    const float* f = (const float*)d_in[0];   // [8192,512] -> 32768 rows of 128
    const float* W = (const float*)d_in[1];   // [2048,128]

    float* loss = (float*)d_out;              // [8192]
    float* outv = (float*)d_out + BATCH;      // [8192*512]

    // fh/fl scratch lives in the outv region (16 MB, exact fit); fully
    // consumed by vq_argmin before gather_kernel overwrites outv.
    _Float16* fhf = (_Float16*)outv;                              // 8 MB
    _Float16* flf = (_Float16*)((char*)outv + 8388608);           // 8 MB

    // workspace layout
    float*    wnorm = (float*)d_ws;                              // @0       (8 KB)
    _Float16* whf   = (_Float16*)((char*)d_ws + 8192);           // @8K    (512 KB)
    _Float16* wlf   = (_Float16*)((char*)d_ws + 532480);         // @520K  (512 KB)
    float*    bsp   = (float*)((char*)d_ws + 1056768);           //        (512 KB)
    int*      bcp   = (int*)((char*)d_ws + 1581056);             //        (512 KB)
    float*    fnorm = (float*)((char*)d_ws + 2105344);           //        (128 KB)

    wconv_kernel<<<KCODES * 16 / 256, 256, 0, stream>>>(W, whf, wlf, wnorm);
    fconv_kernel<<<NROWS * 16 / 256, 256, 0, stream>>>(f, fhf, flf, fnorm);

    hipLaunchKernelGGL(vq_argmin, dim3(512), dim3(512), 0, stream,
                       fhf, flf, whf, wlf, wnorm, bsp, bcp);

    gather_kernel<<<BATCH, 256, 0, stream>>>(W, fnorm, bsp, bcp, loss, outv);
}

// Round 21
// 76.383 us; speedup vs baseline: 3.5771x; 3.5771x over previous
//
#include <hip/hip_runtime.h>

#define D        128
#define KCODES   2048
#define NROWS    32768
#define BATCH    8192

typedef _Float16 f16x8 __attribute__((ext_vector_type(8)));
typedef float    f32x4 __attribute__((ext_vector_type(4)));

#define MFMA16(a, b, c) __builtin_amdgcn_mfma_f32_16x16x32_f16((a), (b), (c), 0, 0, 0)
#define INV2048 4.8828125e-4f

// min-reduce a packed float across each 16-lane row via DPP row_ror (pure VALU)
static __device__ __forceinline__ float dppmin16(float s) {
    int t;
    t = __builtin_amdgcn_update_dpp(0, __float_as_int(s), 0x121, 0xf, 0xf, true);
    s = fminf(s, __int_as_float(t));
    t = __builtin_amdgcn_update_dpp(0, __float_as_int(s), 0x122, 0xf, 0xf, true);
    s = fminf(s, __int_as_float(t));
    t = __builtin_amdgcn_update_dpp(0, __float_as_int(s), 0x124, 0xf, 0xf, true);
    s = fminf(s, __int_as_float(t));
    t = __builtin_amdgcn_update_dpp(0, __float_as_int(s), 0x128, 0xf, 0xf, true);
    s = fminf(s, __int_as_float(t));
    return s;
}

// ---------------------------------------------------------------------------
// Kernel A: W -> (wh, wl) fp16 hi/lo in 16x16x32 fragment-linear layout +
// fp32 ||W||^2.  (layout verified by absmax<=1 in R11-R19)
// ---------------------------------------------------------------------------
__global__ void wconv_kernel(const float* __restrict__ W,
                             _Float16* __restrict__ whf, _Float16* __restrict__ wlf,
                             float* __restrict__ wnorm) {
    int gid = blockIdx.x * 256 + threadIdx.x;    // 32768 = 2048 codes x 16 slots
    int n = gid >> 4, s = gid & 15;
    const float4* src = (const float4*)(W + (size_t)n * D + s * 8);
    float4 a = src[0], b = src[1];
    float va[8] = {a.x, a.y, a.z, a.w, b.x, b.y, b.z, b.w};
    f16x8 hi, lo;
    float ss = 0.0f;
#pragma unroll
    for (int j = 0; j < 8; ++j) {
        _Float16 h = (_Float16)va[j];
        hi[j] = h;
        lo[j] = (_Float16)((va[j] - (float)h) * 2048.0f);
        ss += va[j] * va[j];
    }
    size_t idx = ((size_t)((n >> 4) * 4 + (s >> 2)) * 64 + (s & 3) * 16 + (n & 15));
    ((f16x8*)whf)[idx] = hi;
    ((f16x8*)wlf)[idx] = lo;
#pragma unroll
    for (int m = 1; m <= 8; m <<= 1) ss += __shfl_xor(ss, m);
    if (s == 0) wnorm[n] = ss;
}

// ---------------------------------------------------------------------------
// Kernel A2: f -> (-2f) hi/lo fp16 in the same fragment-linear layout,
// plus fp32 ||f_n||^2 (for the loss; lets gather skip re-reading f).
// ---------------------------------------------------------------------------
__global__ void fconv_kernel(const float* __restrict__ f,
                             _Float16* __restrict__ fhf, _Float16* __restrict__ flf,
                             float* __restrict__ fnorm) {
    int gid = blockIdx.x * 256 + threadIdx.x;    // 524288 = 32768 rows x 16 slots
    int n = gid >> 4, s = gid & 15;
    const float4* src = (const float4*)(f + (size_t)n * D + s * 8);
    float4 a = src[0], b = src[1];
    float va[8] = {a.x, a.y, a.z, a.w, b.x, b.y, b.z, b.w};
    f16x8 hi, lo;
    float ss = 0.0f;
#pragma unroll
    for (int j = 0; j < 8; ++j) {
        ss += va[j] * va[j];
        float x = -2.0f * va[j];
        _Float16 h = (_Float16)x;
        hi[j] = h;
        lo[j] = (_Float16)((x - (float)h) * 2048.0f);
    }
    size_t idx = ((size_t)((n >> 4) * 4 + (s >> 2)) * 64 + (s & 3) * 16 + (n & 15));
    ((f16x8*)fhf)[idx] = hi;
    ((f16x8*)flf)[idx] = lo;
#pragma unroll
    for (int m = 1; m <= 8; m <<= 1) ss += __shfl_xor(ss, m);
    if (s == 0) fnorm[n] = ss;
}

// ---------------------------------------------------------------------------
// Kernel B: W-STATIONARY, barrier-free, CLEAN 4-waves/SIMD TLP TEST.
// Grid 512 = 64 row-groups(512 rows) x 8 code-blocks(256 codes); cb = b&7
// -> one W panel per XCD.  Block 512 thr = 8 waves; wave owns 32 codes
// (wh+wl = 64 VGPR) -> total live ~128 fits the 4-wave VGPR cap WITHOUT
// spill (R20's failure mode).  Rolled main loop (TLP, not ILP, hides
// latency -- that is the variable under test).  Per 16-row tile per wave:
// 8 coalesced loads -> 24 MFMA (4 chains) -> fold + DPP reduce.
// ---------------------------------------------------------------------------
extern "C" __global__ void __launch_bounds__(512)
__attribute__((amdgpu_flat_work_group_size(512, 512)))
__attribute__((amdgpu_waves_per_eu(4, 4)))
vq_argmin(const _Float16* __restrict__ fhf, const _Float16* __restrict__ flf,
          const _Float16* __restrict__ whf, const _Float16* __restrict__ wlf,
          const float* __restrict__ wnorm,
          float* __restrict__ bsp, int* __restrict__ bcp) {
    __shared__ float mrg[8 * 512];           // 16 KB: [wave][block-local row]

    const int b   = blockIdx.x;
    const int cb  = b & 7;                   // code block 0..7 (one per XCD)
    const int rg  = b >> 3;                  // row group 0..63 (512 rows)
    const int tid = threadIdx.x;
    const int w   = tid >> 6, l = tid & 63;
    const int l15 = l & 15, lq = l >> 4;

    // ---- W fragments: 32 codes (2 ct-tiles), hi+lo, in registers (64 VGPR) ----
    f16x8 wh[2][4], wl[2][4];
    {
        const f16x8* whv = (const f16x8*)whf;
        const f16x8* wlv = (const f16x8*)wlf;
        const int n0 = cb * 16 + w * 2;
#pragma unroll
        for (int ct = 0; ct < 2; ++ct)
#pragma unroll
            for (int ks = 0; ks < 4; ++ks) {
                size_t idx = (size_t)((n0 + ct) * 4 + ks) * 64 + l;
                wh[ct][ks] = whv[idx];
                wl[ct][ks] = wlv[idx];
            }
    }
    float wv[2];
    unsigned mv[2];
#pragma unroll
    for (int ct = 0; ct < 2; ++ct) {
        wv[ct] = wnorm[cb * 256 + w * 32 + ct * 16 + l15];
        mv[ct] = (unsigned)(ct << 4) | (unsigned)l15;
    }

    // f fragment base for this row group (512 rows = 32 sixteen-row tiles)
    const f16x8* fhv = (const f16x8*)fhf + (size_t)rg * 8192;
    const f16x8* flv = (const f16x8*)flf + (size_t)rg * 8192;

    // ---- main loop: 32 tiles, rolled, no barriers ----
#pragma unroll 1
    for (int m = 0; m < 32; ++m) {
        f16x8 fhk[4], flk[4];
#pragma unroll
        for (int ks = 0; ks < 4; ++ks) {
            fhk[ks] = fhv[(m * 4 + ks) * 64 + l];
            flk[ks] = flv[(m * 4 + ks) * 64 + l];
        }

        f32x4 accC[2], accH[2];
#pragma unroll
        for (int ct = 0; ct < 2; ++ct)
#pragma unroll
            for (int r = 0; r < 4; ++r) { accC[ct][r] = 0.0f; accH[ct][r] = wv[ct]; }

#pragma unroll
        for (int ks = 0; ks < 4; ++ks) {
            __builtin_amdgcn_s_setprio(1);
            // 6 MFMAs, 4 chains, same-chain gap 4
#pragma unroll
            for (int ct = 0; ct < 2; ++ct)
                accC[ct] = MFMA16(fhk[ks], wl[ct][ks], accC[ct]);
#pragma unroll
            for (int ct = 0; ct < 2; ++ct)
                accH[ct] = MFMA16(fhk[ks], wh[ct][ks], accH[ct]);
#pragma unroll
            for (int ct = 0; ct < 2; ++ct)
                accC[ct] = MFMA16(flk[ks], wh[ct][ks], accC[ct]);
            __builtin_amdgcn_s_setprio(0);
        }

        // ---- fold: per row-slot r, min over 2 ct, (ct,col) in low 5 bits ----
        float bestR[4] = {3.4e38f, 3.4e38f, 3.4e38f, 3.4e38f};
#pragma unroll
        for (int ct = 0; ct < 2; ++ct)
#pragma unroll
            for (int r = 0; r < 4; ++r) {
                float s = fmaf(accC[ct][r], INV2048, accH[ct][r]);
                unsigned pk = (__float_as_uint(s) & 0xFFFFFFE0u) | mv[ct];
                bestR[r] = fminf(bestR[r], __uint_as_float(pk));
            }
        // min over the 16 code-columns (DPP, VALU-only)
#pragma unroll
        for (int r = 0; r < 4; ++r) bestR[r] = dppmin16(bestR[r]);

        if (l15 == 0) {
            f32x4 v;
            v[0] = bestR[0]; v[1] = bestR[1]; v[2] = bestR[2]; v[3] = bestR[3];
            *(f32x4*)(mrg + w * 512 + m * 16 + lq * 4) = v;
        }
    }

    // ---- epilogue: merge 8 waves per row; decode packed meta -> code ----
    __syncthreads();
    {
        int row = tid;                        // 512 rows
        float s = mrg[row];
        int wBest = 0;
#pragma unroll
        for (int ww = 1; ww < 8; ++ww) {
            float s2 = mrg[ww * 512 + row];
            if (s2 < s) { s = s2; wBest = ww; }
        }
        unsigned bits = __float_as_uint(s);
        int code = cb * 256 + wBest * 32 + (int)((bits >> 4) & 1u) * 16 + (int)(bits & 15u);
        bsp[(size_t)cb * NROWS + rg * 512 + row] = s;
        bcp[(size_t)cb * NROWS + rg * 512 + row] = code;
    }
}

// ---------------------------------------------------------------------------
// Kernel C: merge the 8 code-block partials, gather W[j], write out; loss
// computed from the winning score + precomputed ||f||^2 (no f re-read).
// ---------------------------------------------------------------------------
__global__ void gather_kernel(const float* __restrict__ W,
                              const float* __restrict__ fnorm,
                              const float* __restrict__ bsp, const int* __restrict__ bcp,
                              float* __restrict__ loss, float* __restrict__ outv) {
    int b  = blockIdx.x;
    int wv = threadIdx.x >> 6;
    int l  = threadIdx.x & 63;
    int n  = b * 4 + wv;
    float s; int c;
    if (l < 8) { s = bsp[(size_t)l * NROWS + n]; c = bcp[(size_t)l * NROWS + n]; }
    else       { s = 3.4e38f; c = 0x7FFFFFFF; }
#pragma unroll
    for (int msk = 1; msk <= 4; msk <<= 1) {
        float s2 = __shfl_xor(s, msk);
        int   c2 = __shfl_xor(c, msk);
        if (s2 < s || (s2 == s && c2 < c)) { s = s2; c = c2; }
    }
    int j = __shfl(c, 0);
    float smin = __shfl(s, 0);
    float2 wj = reinterpret_cast<const float2*>(W + (size_t)j * D)[l];
    reinterpret_cast<float2*>(outv + (size_t)n * D)[l] = wj;
    __shared__ float lsm[4];
    if (l == 0) lsm[wv] = smin + fnorm[n];   // = ||f_n - W_j||^2 (+ ~1e-3)
    __syncthreads();
    if (threadIdx.x == 0)
        loss[b] = 0.3125f * (lsm[0] + lsm[1] + lsm[2] + lsm[3]);
}

// ---------------------------------------------------------------------------
extern "C" void kernel_launch(void* const* d_in, const int* in_sizes, int n_in,
                              void* d_out, int out_size, void* d_ws, size_t ws_size,
                              hipStream_t stream) {
    const float* f = (const float*)d_in[0];   // [8192,512] -> 32768 rows of 128
    const float* W = (const float*)d_in[1];   // [2048,128]

    float* loss = (float*)d_out;              // [8192]
    float* outv = (float*)d_out + BATCH;      // [8192*512]

    // fh/fl scratch lives in the outv region (16 MB, exact fit); fully
    // consumed by vq_argmin before gather_kernel overwrites outv.
    _Float16* fhf = (_Float16*)outv;                              // 8 MB
    _Float16* flf = (_Float16*)((char*)outv + 8388608);           // 8 MB

    // workspace layout
    float*    wnorm = (float*)d_ws;                              // @0       (8 KB)
    _Float16* whf   = (_Float16*)((char*)d_ws + 8192);           // @8K    (512 KB)
    _Float16* wlf   = (_Float16*)((char*)d_ws + 532480);         // @520K  (512 KB)
    float*    bsp   = (float*)((char*)d_ws + 1056768);           //          (1 MB)
    int*      bcp   = (int*)((char*)d_ws + 2105344);             //          (1 MB)
    float*    fnorm = (float*)((char*)d_ws + 3153920);           //        (128 KB)

    wconv_kernel<<<KCODES * 16 / 256, 256, 0, stream>>>(W, whf, wlf, wnorm);
    fconv_kernel<<<NROWS * 16 / 256, 256, 0, stream>>>(f, fhf, flf, fnorm);

    hipLaunchKernelGGL(vq_argmin, dim3(512), dim3(512), 0, stream,
                       fhf, flf, whf, wlf, wnorm, bsp, bcp);

    gather_kernel<<<BATCH, 256, 0, stream>>>(W, fnorm, bsp, bcp, loss, outv);
}

// Round 22
// 62.269 us; speedup vs baseline: 4.3878x; 1.2266x over previous
//
#include <hip/hip_runtime.h>

#define D        128
#define KCODES   2048
#define NROWS    32768
#define BATCH    8192

typedef _Float16 f16x8 __attribute__((ext_vector_type(8)));
typedef float    f32x4 __attribute__((ext_vector_type(4)));

#define MFMA16(a, b, c) __builtin_amdgcn_mfma_f32_16x16x32_f16((a), (b), (c), 0, 0, 0)
#define INV2048 4.8828125e-4f

// min-reduce a packed float across each 16-lane row via DPP row_ror (pure VALU)
static __device__ __forceinline__ float dppmin16(float s) {
    int t;
    t = __builtin_amdgcn_update_dpp(0, __float_as_int(s), 0x121, 0xf, 0xf, true);
    s = fminf(s, __int_as_float(t));
    t = __builtin_amdgcn_update_dpp(0, __float_as_int(s), 0x122, 0xf, 0xf, true);
    s = fminf(s, __int_as_float(t));
    t = __builtin_amdgcn_update_dpp(0, __float_as_int(s), 0x124, 0xf, 0xf, true);
    s = fminf(s, __int_as_float(t));
    t = __builtin_amdgcn_update_dpp(0, __float_as_int(s), 0x128, 0xf, 0xf, true);
    s = fminf(s, __int_as_float(t));
    return s;
}

// ---------------------------------------------------------------------------
// Kernel A (FUSED prep): blocks [0,128) convert W -> (wh,wl)+wnorm;
// blocks [128, 128+2048) convert f -> (-2f) hi/lo + fnorm.  Both use the
// same 16x16x32 fragment-linear layout (verified absmax<=1, R11-R19):
// for 16-row tile n0, kstep ks, lane slot: elem [n0*16+(n&15)][s*8+j] at
// f16x8 idx ((n0*4 + s>>2)*64 + (s&3)*16 + (n&15)).
// ---------------------------------------------------------------------------
__global__ void prep_kernel(const float* __restrict__ W, const float* __restrict__ f,
                            _Float16* __restrict__ whf, _Float16* __restrict__ wlf,
                            float* __restrict__ wnorm,
                            _Float16* __restrict__ fhf, _Float16* __restrict__ flf,
                            float* __restrict__ fnorm) {
    const bool isW = blockIdx.x < 128;
    int gid = (isW ? blockIdx.x : (blockIdx.x - 128)) * 256 + threadIdx.x;
    int n = gid >> 4, s = gid & 15;
    const float* src0 = isW ? W : f;
    const float4* src = (const float4*)(src0 + (size_t)n * D + s * 8);
    float4 a = src[0], b = src[1];
    float va[8] = {a.x, a.y, a.z, a.w, b.x, b.y, b.z, b.w};
    const float scale = isW ? 1.0f : -2.0f;
    f16x8 hi, lo;
    float ss = 0.0f;
#pragma unroll
    for (int j = 0; j < 8; ++j) {
        ss += va[j] * va[j];
        float x = scale * va[j];
        _Float16 h = (_Float16)x;
        hi[j] = h;
        lo[j] = (_Float16)((x - (float)h) * 2048.0f);
    }
    size_t idx = ((size_t)((n >> 4) * 4 + (s >> 2)) * 64 + (s & 3) * 16 + (n & 15));
    if (isW) { ((f16x8*)whf)[idx] = hi; ((f16x8*)wlf)[idx] = lo; }
    else     { ((f16x8*)fhf)[idx] = hi; ((f16x8*)flf)[idx] = lo; }
#pragma unroll
    for (int m = 1; m <= 8; m <<= 1) ss += __shfl_xor(ss, m);
    if (s == 0) { if (isW) wnorm[n] = ss; else fnorm[n] = ss; }
}

// ---------------------------------------------------------------------------
// Kernel B: W-STATIONARY, f direct from global (L1-cached), BARRIER-FREE.
// (R19 verbatim — measured best: 44.1 us, MfmaUtil 48%, zero spill.)
// Grid 256 = 64 row-groups(512 rows) x 4 code-blocks(512 codes); cb = b&3.
// Block 512 thr = 8 waves; wave w owns 64 codes (wh+wl in 128 VGPRs).
// Per 16-row tile: 8 coalesced loads -> 48 MFMA (16 chains) -> fold+DPP.
// One __syncthreads before the 8-wave mrg merge epilogue.
// ---------------------------------------------------------------------------
extern "C" __global__ void __launch_bounds__(512)
__attribute__((amdgpu_flat_work_group_size(512, 512)))
__attribute__((amdgpu_waves_per_eu(2, 2)))
vq_argmin(const _Float16* __restrict__ fhf, const _Float16* __restrict__ flf,
          const _Float16* __restrict__ whf, const _Float16* __restrict__ wlf,
          const float* __restrict__ wnorm,
          float* __restrict__ bsp, int* __restrict__ bcp) {
    __shared__ float mrg[8 * 512];           // 16 KB: [wave][block-local row]

    const int b   = blockIdx.x;
    const int cb  = b & 3;                   // code block 0..3 (XCD-pinned)
    const int rg  = b >> 2;                  // row group 0..63 (512 rows)
    const int tid = threadIdx.x;
    const int w   = tid >> 6, l = tid & 63;
    const int l15 = l & 15, lq = l >> 4;

    // ---- W fragments: 64 codes (4 ct-tiles), hi+lo, in registers (128 VGPR) ----
    f16x8 wh[4][4], wl[4][4];
    {
        const f16x8* whv = (const f16x8*)whf;
        const f16x8* wlv = (const f16x8*)wlf;
        const int n0 = cb * 32 + w * 4;
#pragma unroll
        for (int ct = 0; ct < 4; ++ct)
#pragma unroll
            for (int ks = 0; ks < 4; ++ks) {
                size_t idx = (size_t)((n0 + ct) * 4 + ks) * 64 + l;
                wh[ct][ks] = whv[idx];
                wl[ct][ks] = wlv[idx];
            }
    }
    float wv[4];
    unsigned mv[4];
#pragma unroll
    for (int ct = 0; ct < 4; ++ct) {
        wv[ct] = wnorm[cb * 512 + w * 64 + ct * 16 + l15];
        mv[ct] = (unsigned)(ct << 4) | (unsigned)l15;
    }

    // f fragment base for this row group (512 rows = 32 sixteen-row tiles)
    const f16x8* fhv = (const f16x8*)fhf + (size_t)rg * 8192;
    const f16x8* flv = (const f16x8*)flf + (size_t)rg * 8192;

    // ---- main loop: 32 tiles, no barriers; compiler prefetches across tiles ----
#pragma unroll 2
    for (int m = 0; m < 32; ++m) {
        f16x8 fhk[4], flk[4];
#pragma unroll
        for (int ks = 0; ks < 4; ++ks) {
            fhk[ks] = fhv[(m * 4 + ks) * 64 + l];
            flk[ks] = flv[(m * 4 + ks) * 64 + l];
        }

        f32x4 accC[4], accH[4];
#pragma unroll
        for (int ct = 0; ct < 4; ++ct)
#pragma unroll
            for (int r = 0; r < 4; ++r) { accC[ct][r] = 0.0f; accH[ct][r] = wv[ct]; }

#pragma unroll
        for (int ks = 0; ks < 4; ++ks) {
            __builtin_amdgcn_s_setprio(1);
            // 12 MFMAs, 16 chains live, same-chain gap 8
#pragma unroll
            for (int ct = 0; ct < 4; ++ct)
                accC[ct] = MFMA16(fhk[ks], wl[ct][ks], accC[ct]);
#pragma unroll
            for (int ct = 0; ct < 4; ++ct)
                accH[ct] = MFMA16(fhk[ks], wh[ct][ks], accH[ct]);
#pragma unroll
            for (int ct = 0; ct < 4; ++ct)
                accC[ct] = MFMA16(flk[ks], wh[ct][ks], accC[ct]);
            __builtin_amdgcn_s_setprio(0);
        }

        // ---- fold: per row-slot r, min over 4 ct, (ct,col) in low 6 bits ----
        float bestR[4] = {3.4e38f, 3.4e38f, 3.4e38f, 3.4e38f};
#pragma unroll
        for (int ct = 0; ct < 4; ++ct)
#pragma unroll
            for (int r = 0; r < 4; ++r) {
                float s = fmaf(accC[ct][r], INV2048, accH[ct][r]);
                unsigned pk = (__float_as_uint(s) & 0xFFFFFFC0u) | mv[ct];
                bestR[r] = fminf(bestR[r], __uint_as_float(pk));
            }
        // min over the 16 code-columns (DPP, VALU-only)
#pragma unroll
        for (int r = 0; r < 4; ++r) bestR[r] = dppmin16(bestR[r]);

        if (l15 == 0) {
            f32x4 v;
            v[0] = bestR[0]; v[1] = bestR[1]; v[2] = bestR[2]; v[3] = bestR[3];
            *(f32x4*)(mrg + w * 512 + m * 16 + lq * 4) = v;
        }
    }

    // ---- epilogue: merge 8 waves per row; decode packed meta -> code ----
    __syncthreads();
    {
        int row = tid;                        // 512 rows
        float s = mrg[row];
        int wBest = 0;
#pragma unroll
        for (int ww = 1; ww < 8; ++ww) {
            float s2 = mrg[ww * 512 + row];
            if (s2 < s) { s = s2; wBest = ww; }
        }
        unsigned bits = __float_as_uint(s);
        int code = cb * 512 + wBest * 64 + (int)((bits >> 4) & 3u) * 16 + (int)(bits & 15u);
        bsp[(size_t)cb * NROWS + rg * 512 + row] = s;
        bcp[(size_t)cb * NROWS + rg * 512 + row] = code;
    }
}

// ---------------------------------------------------------------------------
// Kernel C: merge the 4 code-block partials, gather W[j], write out; loss
// computed from the winning score + precomputed ||f||^2 (no f re-read).
// ---------------------------------------------------------------------------
__global__ void gather_kernel(const float* __restrict__ W,
                              const float* __restrict__ fnorm,
                              const float* __restrict__ bsp, const int* __restrict__ bcp,
                              float* __restrict__ loss, float* __restrict__ outv) {
    int b  = blockIdx.x;
    int wv = threadIdx.x >> 6;
    int l  = threadIdx.x & 63;
    int n  = b * 4 + wv;
    float s; int c;
    if (l < 4) { s = bsp[(size_t)l * NROWS + n]; c = bcp[(size_t)l * NROWS + n]; }
    else       { s = 3.4e38f; c = 0x7FFFFFFF; }
#pragma unroll
    for (int msk = 1; msk <= 2; msk <<= 1) {
        float s2 = __shfl_xor(s, msk);
        int   c2 = __shfl_xor(c, msk);
        if (s2 < s || (s2 == s && c2 < c)) { s = s2; c = c2; }
    }
    int j = __shfl(c, 0);
    float smin = __shfl(s, 0);
    float2 wj = reinterpret_cast<const float2*>(W + (size_t)j * D)[l];
    reinterpret_cast<float2*>(outv + (size_t)n * D)[l] = wj;
    __shared__ float lsm[4];
    if (l == 0) lsm[wv] = smin + fnorm[n];   // = ||f_n - W_j||^2 (+ ~1e-3)
    __syncthreads();
    if (threadIdx.x == 0)
        loss[b] = 0.3125f * (lsm[0] + lsm[1] + lsm[2] + lsm[3]);
}

// ---------------------------------------------------------------------------
extern "C" void kernel_launch(void* const* d_in, const int* in_sizes, int n_in,
                              void* d_out, int out_size, void* d_ws, size_t ws_size,
                              hipStream_t stream) {
    const float* f = (const float*)d_in[0];   // [8192,512] -> 32768 rows of 128
    const float* W = (const float*)d_in[1];   // [2048,128]

    float* loss = (float*)d_out;              // [8192]
    float* outv = (float*)d_out + BATCH;      // [8192*512]

    // fh/fl scratch lives in the outv region (16 MB, exact fit); fully
    // consumed by vq_argmin before gather_kernel overwrites outv.
    _Float16* fhf = (_Float16*)outv;                              // 8 MB
    _Float16* flf = (_Float16*)((char*)outv + 8388608);           // 8 MB

    // workspace layout
    float*    wnorm = (float*)d_ws;                              // @0       (8 KB)
    _Float16* whf   = (_Float16*)((char*)d_ws + 8192);           // @8K    (512 KB)
    _Float16* wlf   = (_Float16*)((char*)d_ws + 532480);         // @520K  (512 KB)
    float*    bsp   = (float*)((char*)d_ws + 1056768);           //        (512 KB)
    int*      bcp   = (int*)((char*)d_ws + 1581056);             //        (512 KB)
    float*    fnorm = (float*)((char*)d_ws + 2105344);           //        (128 KB)

    // fused prep: 128 W-blocks + 2048 f-blocks
    prep_kernel<<<128 + NROWS * 16 / 256, 256, 0, stream>>>(
        W, f, whf, wlf, wnorm, fhf, flf, fnorm);

    hipLaunchKernelGGL(vq_argmin, dim3(256), dim3(512), 0, stream,
                       fhf, flf, whf, wlf, wnorm, bsp, bcp);

    gather_kernel<<<BATCH, 256, 0, stream>>>(W, fnorm, bsp, bcp, loss, outv);
}